// Round 4
// baseline (490.688 us; speedup 1.0000x reference)
//
#include <hip/hip_runtime.h>

// GAT fused kernel for MI355X (gfx950) -- round 4.
// B=32768 graphs, N=14 nodes, F=C=128, E=64 edges (+14 self loops).
// Inputs f32 (edge_list int32); output f32: pred[32768] ++ attn[32768*196].
//
// Round-3 post-mortem: 211us but ~55k cycles/wave-graph vs ~6k of issue work:
// latency-bound on 64 per-graph L2 loads of W-fragments (L1 thrashed, ~400cyc
// each, poorly overlapped). This round:
//  1. W-fragments (both layers, 64KB, fragment-ordered) staged ONCE per block
//     into LDS; B-frag reads are conflict-free ds_read_b128 (lane-contiguous).
//     Amortized over 16 graphs/block -> W L2 traffic 2.1GB -> 134MB.
//  2. 1024-thr blocks (16 waves = 16 graphs); one __syncthreads after staging.
//  3. WaveLds 8912->6016B: ht stride 16, Pb [16][16], Pf [14][16], and attn
//     recomputed at flush from asn/adn/mz + edge-existence bitmask (kills the
//     attn zero/write/flush LDS phases). LDS total 161,792B <= 160KB.
//  4. Feature f32 loads issued before staging (HBM latency hides under copy).

#define NEG_SLOPE 0.2f

typedef __bf16 bf16x8 __attribute__((ext_vector_type(8)));
typedef float f32x4 __attribute__((ext_vector_type(4)));
typedef unsigned short us4v __attribute__((ext_vector_type(4)));
typedef unsigned short us8v __attribute__((ext_vector_type(8)));

static __device__ __forceinline__ unsigned short f2bf(float f) {
  unsigned u = __builtin_bit_cast(unsigned, f);
  return (unsigned short)((u + 0x7FFFu + ((u >> 16) & 1u)) >> 16); // RNE, finite
}

// ---------------- setup: W frags (bf16, wave-load order) + weffc ----------------
// wfrag short offset: (((lr*4+ks)*8+t)*64 + lane)*8 ; element j = W[ks*32+q*8+j][t*16+l]
// weffc[(t*64+lane)*4+r] = (4q+r)<14 ? sum_c Wl[((4q+r)*128+t*16+l)*64+c]*Wp[c] : 0
__global__ void gat_setup_kernel(const float* __restrict__ W1, const float* __restrict__ W2,
                                 const float* __restrict__ Wl, const float* __restrict__ bl,
                                 const float* __restrict__ Wp, const float* __restrict__ bp,
                                 unsigned short* __restrict__ wfrag, float* __restrict__ weffc) {
  const int blk = blockIdx.x, tid = threadIdx.x; // 17 blocks x 256
  if (blk < 16) {
    int slot = blk * 256 + tid; // (lr,ks,t,lane)
    int lane = slot & 63, t = (slot >> 6) & 7, ks = (slot >> 9) & 3, lr = slot >> 11;
    const float* W = lr ? W2 : W1;
    int q = lane >> 4, l = lane & 15;
    int n = t * 16 + l, k0 = ks * 32 + q * 8;
    us8v hv;
    #pragma unroll
    for (int j = 0; j < 8; ++j) hv[j] = f2bf(W[(k0 + j) * 128 + n]);
    *(us8v*)(wfrag + slot * 8) = hv;
  } else {
    for (int i = tid; i < 2048; i += 256) {
      int r = i & 3, lane = (i >> 2) & 63, t = i >> 8;
      int q = lane >> 4, l = lane & 15;
      int row = 4 * q + r, col = t * 16 + l;
      float s = 0.f;
      if (row < 14) {
        const float* wl = Wl + (size_t)(row * 128 + col) * 64;
        #pragma unroll 8
        for (int c = 0; c < 64; ++c) s += wl[c] * Wp[c];
      }
      weffc[i] = s;
    }
    if (tid == 0) {
      float s = 0.f;
      for (int c = 0; c < 64; ++c) s += bl[c] * Wp[c];
      weffc[2048] = s + bp[0];
    }
  }
}

// Wave-private LDS scratch, 6016 B.
struct __align__(16) WaveLds {
  unsigned short xh[2176]; // xg[16][136] (layer-2 A-op) UNION ht[128][16] (P@h B-op)
  unsigned short Pb[256];  // bf16 P [16][16] (P@h A-op)
  float Pf[224];           // unnormalized P f32 [14][16] [dst][src] (atomicAdd)
  float asn[16], adn[16], mz[16];
  int emask[16];           // per-src bitmask of existing dsts
};

__global__ __launch_bounds__(1024, 4) void gat_kernel(
    const float* __restrict__ feat, const int* __restrict__ edges,
    const float* __restrict__ as1v, const float* __restrict__ ad1v,
    const float* __restrict__ b1v, const float* __restrict__ as2v,
    const float* __restrict__ ad2v, const float* __restrict__ b2v,
    const unsigned short* __restrict__ wfrag, const float* __restrict__ weffc,
    float* __restrict__ out) {
  __shared__ unsigned short sW[32768]; // 64 KB: both layers' B-frags, linear order
  __shared__ WaveLds wls[16];

  const int tid = threadIdx.x;
  const int wave = tid >> 6, lane = tid & 63;
  const int q = lane >> 4, l = lane & 15;
  const int g = blockIdx.x * 16 + wave;
  WaveLds& S = wls[wave];

  // ---- issue feature loads early (raw f32), overlap with W staging ----
  f32x4 fv[8];
  if (l < 14) {
    const float* fb = feat + (size_t)g * 1792 + l * 128 + q * 8;
    #pragma unroll
    for (int ks = 0; ks < 4; ++ks) {
      fv[2 * ks] = *(const f32x4*)(fb + ks * 32);
      fv[2 * ks + 1] = *(const f32x4*)(fb + ks * 32 + 4);
    }
  } else {
    #pragma unroll
    for (int c = 0; c < 8; ++c) fv[c] = (f32x4){0.f, 0.f, 0.f, 0.f};
  }
  // edge endpoints, one edge per lane (E=64)
  int esrc, edst;
  { const int2 e2 = *(const int2*)(edges + (size_t)g * 128 + lane * 2); esrc = e2.x; edst = e2.y; }
  if (lane < 16) S.emask[lane] = 0; // ordered by the staging barrier below

  // ---- stage both layers' W frags: 64KB, linear, coalesced, conflict-free ----
  #pragma unroll
  for (int it = 0; it < 4; ++it) {
    int off = it * 1024 + tid;
    *(us8v*)(&sW[off * 8]) = *(const us8v*)(wfrag + off * 8);
  }
  __syncthreads(); // the only block-wide barrier

  atomicOr(&S.emask[esrc], 1 << edst);
  if (lane < 14) atomicOr(&S.emask[lane], 1 << lane);

  us8v z8v = {0, 0, 0, 0, 0, 0, 0, 0};
  const bf16x8 zf = __builtin_bit_cast(bf16x8, z8v);

  // layer-1 A-fragments from the prefetched feature
  bf16x8 af1[4];
  #pragma unroll
  for (int ks = 0; ks < 4; ++ks) {
    us8v hv;
    hv[0] = f2bf(fv[2 * ks][0]); hv[1] = f2bf(fv[2 * ks][1]);
    hv[2] = f2bf(fv[2 * ks][2]); hv[3] = f2bf(fv[2 * ks][3]);
    hv[4] = f2bf(fv[2 * ks + 1][0]); hv[5] = f2bf(fv[2 * ks + 1][1]);
    hv[6] = f2bf(fv[2 * ks + 1][2]); hv[7] = f2bf(fv[2 * ks + 1][3]);
    af1[ks] = __builtin_bit_cast(bf16x8, hv);
  }

  f32x4 oacc[8];

  for (int lr = 0; lr < 2; ++lr) {
    const float* asv = lr ? as2v : as1v;
    const float* adv = lr ? ad2v : ad1v;
    const float* bsv = lr ? b2v : b1v;

    // ---- h = x @ W (M=16, N=128 in 8 tiles, K=128 in 4 steps); B-frags from LDS ----
    f32x4 hacc[8];
    #pragma unroll
    for (int t = 0; t < 8; ++t) hacc[t] = (f32x4){0.f, 0.f, 0.f, 0.f};
    #pragma unroll
    for (int ks = 0; ks < 4; ++ks) {
      bf16x8 af = lr ? *(const bf16x8*)(&S.xh[l * 136 + ks * 32 + q * 8]) : af1[ks];
      const unsigned short* wk = sW + (lr * 4 + ks) * 4096 + lane * 8;
      #pragma unroll
      for (int t = 0; t < 8; ++t) {
        bf16x8 bfv = *(const bf16x8*)(wk + t * 512); // ds_read_b128, 0 conflicts
        hacc[t] = __builtin_amdgcn_mfma_f32_16x16x32_bf16(af, bfv, hacc[t], 0, 0, 0);
      }
    }

    // ---- node scores: per-lane partial over cols, butterfly over l ----
    f32x4 pas = {0.f, 0.f, 0.f, 0.f}, padv = {0.f, 0.f, 0.f, 0.f};
    #pragma unroll
    for (int t = 0; t < 8; ++t) {
      float ca = asv[t * 16 + l], cd = adv[t * 16 + l]; // 512B, L2-hot
      pas += hacc[t] * ca;
      padv += hacc[t] * cd;
    }
    #pragma unroll
    for (int m = 1; m <= 8; m <<= 1) {
      #pragma unroll
      for (int r = 0; r < 4; ++r) {
        pas[r] += __shfl_xor(pas[r], m, 64);
        padv[r] += __shfl_xor(padv[r], m, 64);
      }
    }
    if (l == 0) {
      #pragma unroll
      for (int r = 0; r < 4; ++r) { S.asn[4 * q + r] = pas[r]; S.adn[4 * q + r] = padv[r]; }
    }

    // ---- h -> ht[128][16] bf16 (B-op of P@h): ht[col][node] ----
    #pragma unroll
    for (int t = 0; t < 8; ++t) {
      us4v hv;
      hv[0] = f2bf(hacc[t][0]); hv[1] = f2bf(hacc[t][1]);
      hv[2] = f2bf(hacc[t][2]); hv[3] = f2bf(hacc[t][3]);
      *(us4v*)(&S.xh[(t * 16 + l) * 16 + q * 4]) = hv;
    }
    if (lane < 56) *(f32x4*)(&S.Pf[lane * 4]) = (f32x4){0.f, 0.f, 0.f, 0.f};
    __threadfence_block();

    // ---- edges: ev = exp(leaky(asn[src]+adn[dst])); accumulate unnormalized P ----
    float f0 = S.asn[esrc] + S.adn[edst];
    float ev = __expf(f0 > 0.f ? f0 : NEG_SLOPE * f0);
    atomicAdd(&S.Pf[edst * 16 + esrc], ev);
    if (lane < 14) { // self loops
      float f2 = S.asn[lane] + S.adn[lane];
      atomicAdd(&S.Pf[lane * 17], __expf(f2 > 0.f ? f2 : NEG_SLOPE * f2));
    }
    __threadfence_block();

    // ---- per-dst 1/z = 1/rowsum(Pf) ----
    if (lane < 14) {
      f32x4 s0 = *(const f32x4*)(&S.Pf[lane * 16]) + *(const f32x4*)(&S.Pf[lane * 16 + 4]) +
                 *(const f32x4*)(&S.Pf[lane * 16 + 8]) + *(const f32x4*)(&S.Pf[lane * 16 + 12]);
      S.mz[lane] = 1.f / (s0[0] + s0[1] + s0[2] + s0[3]);
    }
    __threadfence_block();

    // ---- Pb = bf16(Pf * mz[row]) [16][16]; rows/cols >=14 zeroed ----
    #pragma unroll
    for (int i = lane; i < 256; i += 64) {
      int r = i >> 4, c = i & 15;
      S.Pb[i] = (r < 14 && c < 14) ? f2bf(S.Pf[i] * S.mz[r]) : (unsigned short)0;
    }
    __threadfence_block();

    // ---- out = P @ h + b (K=32; quads>=2 feed zero frags) ----
    #pragma unroll
    for (int t = 0; t < 8; ++t) {
      float bb = bsv[t * 16 + l];
      oacc[t] = (f32x4){bb, bb, bb, bb};
    }
    bf16x8 paf = (q < 2) ? *(const bf16x8*)(&S.Pb[l * 16 + q * 8]) : zf;
    #pragma unroll
    for (int t = 0; t < 8; ++t) {
      bf16x8 hbf = (q < 2) ? *(const bf16x8*)(&S.xh[(t * 16 + l) * 16 + q * 8]) : zf;
      oacc[t] = __builtin_amdgcn_mfma_f32_16x16x32_bf16(paf, hbf, oacc[t], 0, 0, 0);
    }

    if (lr == 0) {
      // x2 = relu(out1) -> xg[16][136]; rows 14/15 = relu(0 + b1) = 0 (b1 == 0)
      __threadfence_block();
      #pragma unroll
      for (int t = 0; t < 8; ++t) {
        #pragma unroll
        for (int r = 0; r < 4; ++r) {
          float v = fmaxf(oacc[t][r], 0.f);
          S.xh[(4 * q + r) * 136 + t * 16 + l] = f2bf(v);
        }
      }
      __threadfence_block();
    }
  }

  // ---- pred = sigmoid(sum oacc .* weffc + beff); weffc pre-masked rows>=14 ----
  float part = 0.f;
  #pragma unroll
  for (int t = 0; t < 8; ++t) {
    f32x4 wv = *(const f32x4*)(weffc + t * 256 + lane * 4); // coalesced, L2-hot
    part += oacc[t][0] * wv[0] + oacc[t][1] * wv[1] + oacc[t][2] * wv[2] + oacc[t][3] * wv[3];
  }
  #pragma unroll
  for (int m = 1; m < 64; m <<= 1) part += __shfl_xor(part, m, 64);
  if (lane == 0) out[g] = 1.f / (1.f + __expf(-(part + weffc[2048])));

  // ---- attn flush: alpha recomputed from asn/adn/mz (layer-2 values) + emask ----
  {
    float* oa = out + 32768 + (size_t)g * 196;
    #pragma unroll
    for (int k = 0; k < 4; ++k) {
      int i = lane + k * 64;
      if (i < 196) {
        int s = (i * 4682) >> 16; // floor(i/14) for i in [0,196)
        int d = i - s * 14;
        float a = 0.f;
        if ((S.emask[s] >> d) & 1) {
          float f = S.asn[s] + S.adn[d];
          a = __expf(f > 0.f ? f : NEG_SLOPE * f) * S.mz[d];
        }
        oa[i] = a;
      }
    }
  }
}

extern "C" void kernel_launch(void* const* d_in, const int* in_sizes, int n_in,
                              void* d_out, int out_size, void* d_ws, size_t ws_size,
                              hipStream_t stream) {
  const float* feat = (const float*)d_in[0];
  const int* edges = (const int*)d_in[1];
  const float* W1 = (const float*)d_in[2];
  const float* as1 = (const float*)d_in[3];
  const float* ad1 = (const float*)d_in[4];
  const float* b1 = (const float*)d_in[5];
  const float* W2 = (const float*)d_in[6];
  const float* as2 = (const float*)d_in[7];
  const float* ad2 = (const float*)d_in[8];
  const float* b2 = (const float*)d_in[9];
  const float* Wl = (const float*)d_in[10];
  const float* bl = (const float*)d_in[11];
  const float* Wp = (const float*)d_in[12];
  const float* bp = (const float*)d_in[13];

  unsigned short* wfrag = (unsigned short*)d_ws;          // 65536 B
  float* weffc = (float*)((char*)d_ws + 65536);           // 2049 f32

  gat_setup_kernel<<<17, 256, 0, stream>>>(W1, W2, Wl, bl, Wp, bp, wfrag, weffc);
  gat_kernel<<<2048, 1024, 0, stream>>>(feat, edges, as1, ad1, b1, as2, ad2, b2,
                                        wfrag, weffc, (float*)d_out);
}